// Round 14
// baseline (144.363 us; speedup 1.0000x reference)
//
#include <hip/hip_runtime.h>
#include <hip/hip_bf16.h>

typedef unsigned short u16;
typedef __attribute__((ext_vector_type(8))) short bf16x8;
typedef __attribute__((ext_vector_type(4))) float f32x4;

typedef const __attribute__((address_space(1))) void gvoid_t;
typedef __attribute__((address_space(3))) void lvoid_t;

__device__ __forceinline__ void gload_lds16(const void* g, void* l) {
  __builtin_amdgcn_global_load_lds((gvoid_t*)g, (lvoid_t*)l, 16, 0, 0);
}

__device__ __forceinline__ u16 f2bf(float f) {
  union { float f; unsigned u; } a;
  a.f = f;
  unsigned r = (a.u + 0x7FFFu + ((a.u >> 16) & 1u)) >> 16;  // RN-even
  return (u16)r;
}

// ---------------------------------------------------------------------------
// Prep: fp32 -> bf16 copies of x and y, plus per-row sum of squares.
// ---------------------------------------------------------------------------
__global__ __launch_bounds__(128) void rbf_prep(
    const float* __restrict__ x, const float* __restrict__ y,
    u16* __restrict__ xb, u16* __restrict__ yb,
    float* __restrict__ xsq, float* __restrict__ ysq,
    int N, int M, int D) {
  int row = blockIdx.x;
  const float* src;
  u16* dst;
  float* sq;
  if (row < N) {
    src = x + (size_t)row * D;
    dst = xb + (size_t)row * D;
    sq = xsq + row;
  } else {
    int r = row - N;
    src = y + (size_t)r * D;
    dst = yb + (size_t)r * D;
    sq = ysq + r;
  }
  int t = threadIdx.x;
  float4 v = reinterpret_cast<const float4*>(src)[t];
  float s = v.x * v.x + v.y * v.y + v.z * v.z + v.w * v.w;
  ushort4 o;
  o.x = f2bf(v.x);
  o.y = f2bf(v.y);
  o.z = f2bf(v.z);
  o.w = f2bf(v.w);
  reinterpret_cast<ushort4*>(dst)[t] = o;
  #pragma unroll
  for (int off = 32; off > 0; off >>= 1) s += __shfl_down(s, off, 64);
  __shared__ float red[2];
  if ((t & 63) == 0) red[t >> 6] = s;
  __syncthreads();
  if (t == 0) sq[0] = red[0] + red[1];
}

// ---------------------------------------------------------------------------
// R14: WAVE-PRIVATE LDS, ZERO-BARRIER streaming GEMM.
// The untried cell: R11 proved wave-independence w/ direct-global operands
// fails (L1 thrash / L2 latency serial); R5-family proved LDS staging works
// but carries the barrier convoy. Combination: each wave owns a 64x64 tile
// with PRIVATE x/y LDS buffers (BK=32, 2-deep: 4 waves x 2 bufs x 2 ops x
// 4 KB = 64 KB -> 2 blocks/CU = 8 self-paced wave-pipelines/CU, ZERO
// s_barrier in the kernel). Hazards become wave-local:
//   visibility: top-of-iter counted vmcnt(8) = my tile-t DMA done;
//   WAR: lgkmcnt(0) (reads in regs) precedes stage(t+2) into same buffer.
// BK=32 linear layout is bank-OPTIMAL for both ds_read_b128 frags and DMA
// writes (row=64B: every bank gets exactly 8x4B per wave-instr; verified
// arithmetic, R7). Per K-tile: vmcnt -> 8 ds_read -> lgkmcnt(0) ->
// issue stage(t+2) -> 16 MFMA; unrolled x2 for static buffer indexing.
// Swapped MFMA operands -> D[j][i] -> float4 stores; column-band supertile;
// exp2-fused epilogue with hoisted norms (R13).
// ---------------------------------------------------------------------------
#define BM 128
#define BN 128
#define BK 32

__global__ __launch_bounds__(256, 2) void rbf_gemm(
    const u16* __restrict__ xb, const u16* __restrict__ yb,
    const float* __restrict__ xsq, const float* __restrict__ ysq,
    const float* __restrict__ gptr, float* __restrict__ out,
    int N, int M, int D) {
  __shared__ u16 lds[4][2][2][64 * BK];  // [wave][buf][op] = 64 KiB

  int bid = blockIdx.x;
  int nbr = N / BM, nbc = M / BN;
  int trow, tcol;
  if (nbr == 64 && nbc == 64) {
    // XCD x owns tile-columns x*8..x*8+7, walked in 8x8-tile regions
    // (column-major inside a region): panels stay L2-resident per XCD.
    int xcd = bid & 7;
    int s = bid >> 3;        // 0..511
    int gr = s >> 6;         // region row 0..7
    int q = s & 63;          // within-region, column-major
    trow = gr * 8 + (q & 7);
    tcol = xcd * 8 + (q >> 3);
  } else {
    int cpx = gridDim.x >> 3;
    int swz = (bid & 7) * cpx + (bid >> 3);
    trow = swz / nbc;
    tcol = swz % nbc;
  }

  int tid = threadIdx.x;
  int w = tid >> 6;       // wave 0..3 (fully independent; never synced)
  int lane = tid & 63;
  int wm = w >> 1;        // 0..1 row half (64 rows)
  int wn = w & 1;         // 0..1 col half (64 cols)
  int fr = lane & 15;
  int fq = lane >> 4;

  int brow = trow * BM + wm * 64;   // this wave's x rows (out rows i)
  int bcol = tcol * BN + wn * 64;   // this wave's y rows (out cols j)

  // --- staging: wave stages its own 64x32 x-tile and y-tile.
  // One gload instr = 64 lanes x 16B = 16 rows (row = 64 B at BK=32).
  int srow = lane >> 2;                 // 0..15
  int schunk = (lane & 3) * 8;          // elems (16B chunks)
  const u16* xsrc = xb + (size_t)(brow + srow) * D + schunk;
  const u16* ysrc = yb + (size_t)(bcol + srow) * D + schunk;
  u16* myx[2] = {&lds[0][0][0][0], &lds[0][0][0][0]};
  // (initialized properly below; avoids dynamic [w] in hot loop)
  myx[0] = &lds[w][0][0][0];
  myx[1] = &lds[w][1][0][0];
  u16* myy[2];
  myy[0] = &lds[w][0][1][0];
  myy[1] = &lds[w][1][1][0];

  // --- fragment read offsets (linear, bank-optimal) ---
  int colf = fq * 8;
  int arow0 = fr * BK + colf;   // + m*16*BK

  // --- hoisted epilogue constants & norm loads ---
  float gl2 = gptr[0] * 1.44269504088896f;  // gamma * log2(e)
  float m2gl2 = 2.0f * gl2;
  float gxs[4];
  float4 gys[4];
  #pragma unroll
  for (int m = 0; m < 4; ++m) gxs[m] = gl2 * xsq[brow + m * 16 + fr];
  #pragma unroll
  for (int n = 0; n < 4; ++n) {
    float4 t4 = *reinterpret_cast<const float4*>(&ysq[bcol + n * 16 + fq * 4]);
    gys[n].x = gl2 * t4.x;
    gys[n].y = gl2 * t4.y;
    gys[n].z = gl2 * t4.z;
    gys[n].w = gl2 * t4.w;
  }

  f32x4 acc[4][4];
  #pragma unroll
  for (int m = 0; m < 4; ++m)
    #pragma unroll
    for (int n = 0; n < 4; ++n)
      acc[m][n] = (f32x4){0.f, 0.f, 0.f, 0.f};

#define STAGE(KT, B)                                                           \
  {                                                                            \
    const u16* xs_ = xsrc + (KT) * BK;                                         \
    const u16* ys_ = ysrc + (KT) * BK;                                         \
    _Pragma("unroll") for (int i = 0; i < 4; ++i)                              \
      gload_lds16(xs_ + (size_t)i * 16 * D, myx[B] + i * 512);                 \
    _Pragma("unroll") for (int i = 0; i < 4; ++i)                              \
      gload_lds16(ys_ + (size_t)i * 16 * D, myy[B] + i * 512);                 \
  }

#define BODY(T, B)                                                             \
  {                                                                            \
    const int t_ = (T);                                                        \
    if (t_ + 1 < nkt)                                                          \
      asm volatile("s_waitcnt vmcnt(8)" ::: "memory");                         \
    else                                                                       \
      asm volatile("s_waitcnt vmcnt(0)" ::: "memory");                         \
    __builtin_amdgcn_sched_barrier(0);                                         \
    const u16* A = myx[B];                                                     \
    const u16* Bp = myy[B];                                                    \
    bf16x8 af[4], bf[4];                                                       \
    _Pragma("unroll") for (int m = 0; m < 4; ++m)                              \
        af[m] = *(const bf16x8*)&A[arow0 + m * 16 * BK];                       \
    _Pragma("unroll") for (int n = 0; n < 4; ++n)                              \
        bf[n] = *(const bf16x8*)&Bp[arow0 + n * 16 * BK];                      \
    asm volatile("s_waitcnt lgkmcnt(0)" ::: "memory");                         \
    __builtin_amdgcn_sched_barrier(0);                                         \
    if (t_ + 2 < nkt) STAGE(t_ + 2, B)                                         \
    _Pragma("unroll") for (int m = 0; m < 4; ++m)                              \
      _Pragma("unroll") for (int n = 0; n < 4; ++n)                            \
        acc[m][n] = __builtin_amdgcn_mfma_f32_16x16x32_bf16(                   \
            bf[n], af[m], acc[m][n], 0, 0, 0);                                 \
  }

  int nkt = D >> 5;  // 16 (even; guarded in launcher)
  STAGE(0, 0)
  STAGE(1, 1)
  for (int tp = 0; tp < nkt; tp += 2) {
    BODY(tp, 0)
    BODY(tp + 1, 1)
  }
#undef BODY
#undef STAGE

  // Epilogue: out = exp2(2*gl2*acc - gl2*|x|^2 - gl2*|y|^2), clamped <= 2^0.
  // Swapped layout: i = fr (row), j = fq*4 + r (col) -> float4 stores.
  #pragma unroll
  for (int m = 0; m < 4; ++m) {
    int i = brow + m * 16 + fr;
    size_t ro = (size_t)i * M;
    #pragma unroll
    for (int n = 0; n < 4; ++n) {
      int jb = bcol + n * 16 + fq * 4;
      float4 e;
      e.x = exp2f(fminf(fmaf(m2gl2, acc[m][n][0], -(gxs[m] + gys[n].x)), 0.f));
      e.y = exp2f(fminf(fmaf(m2gl2, acc[m][n][1], -(gxs[m] + gys[n].y)), 0.f));
      e.z = exp2f(fminf(fmaf(m2gl2, acc[m][n][2], -(gxs[m] + gys[n].z)), 0.f));
      e.w = exp2f(fminf(fmaf(m2gl2, acc[m][n][3], -(gxs[m] + gys[n].w)), 0.f));
      *reinterpret_cast<float4*>(&out[ro + jb]) = e;
    }
  }
}

// ---------------------------------------------------------------------------
// Fallback: fp32 LDS-tiled, slow but correct for odd shapes.
// ---------------------------------------------------------------------------
__global__ __launch_bounds__(256) void rbf_naive(
    const float* __restrict__ x, const float* __restrict__ y,
    const float* __restrict__ gptr, float* __restrict__ out,
    int N, int M, int D) {
  __shared__ float xs[16][17];
  __shared__ float ys[16][17];
  int nbn = M / 16;
  int brow = (blockIdx.x / nbn) * 16;
  int bcol = (blockIdx.x % nbn) * 16;
  int ti = threadIdx.x >> 4, tj = threadIdx.x & 15;
  float dacc = 0.f, xacc = 0.f, yacc = 0.f;
  for (int k0 = 0; k0 < D; k0 += 16) {
    xs[ti][tj] = x[(size_t)(brow + ti) * D + k0 + tj];
    ys[ti][tj] = y[(size_t)(bcol + ti) * D + k0 + tj];
    __syncthreads();
    #pragma unroll
    for (int kk = 0; kk < 16; ++kk) {
      float xv = xs[ti][kk], yv = ys[tj][kk];
      dacc += xv * yv;
      xacc += xv * xv;
      yacc += yv * yv;
    }
    __syncthreads();
  }
  float gamma = gptr[0];
  float d2 = fmaxf(xacc + yacc - 2.f * dacc, 0.f);
  out[(size_t)(brow + ti) * M + (bcol + tj)] = __expf(-gamma * d2);
}

// ---------------------------------------------------------------------------
extern "C" void kernel_launch(void* const* d_in, const int* in_sizes, int n_in,
                              void* d_out, int out_size, void* d_ws,
                              size_t ws_size, hipStream_t stream) {
  const float* x = (const float*)d_in[0];
  const float* y = (const float*)d_in[1];
  const float* g = (const float*)d_in[2];
  float* out = (float*)d_out;

  const int D = 512;
  const int N = in_sizes[0] / D;
  const int M = in_sizes[1] / D;

  size_t need = (size_t)(N + M) * D * sizeof(u16) + (size_t)(N + M) * sizeof(float);
  bool shapes_ok = (N % BM == 0) && (M % BN == 0) && (D % BK == 0) &&
                   ((D / BK) >= 4) && (((D / BK) & 1) == 0);

  if (ws_size >= need && shapes_ok) {
    u16* xb = (u16*)d_ws;
    u16* yb = xb + (size_t)N * D;
    float* xsq = (float*)(yb + (size_t)M * D);
    float* ysq = xsq + N;

    rbf_prep<<<N + M, 128, 0, stream>>>(x, y, xb, yb, xsq, ysq, N, M, D);
    int nwg = (N / BM) * (M / BN);
    rbf_gemm<<<nwg, 256, 0, stream>>>(xb, yb, xsq, ysq, g, out, N, M, D);
  } else {
    rbf_naive<<<(N / 16) * (M / 16), 256, 0, stream>>>(x, y, g, out, N, M, D);
  }
}

// Round 15
// 112.478 us; speedup vs baseline: 1.2835x; 1.2835x over previous
//
#include <hip/hip_runtime.h>
#include <hip/hip_bf16.h>

typedef unsigned short u16;
typedef __attribute__((ext_vector_type(8))) short bf16x8;
typedef __attribute__((ext_vector_type(4))) float f32x4;

typedef const __attribute__((address_space(1))) void gvoid_t;
typedef __attribute__((address_space(3))) void lvoid_t;

__device__ __forceinline__ void gload_lds16(const void* g, void* l) {
  __builtin_amdgcn_global_load_lds((gvoid_t*)g, (lvoid_t*)l, 16, 0, 0);
}

__device__ __forceinline__ u16 f2bf(float f) {
  union { float f; unsigned u; } a;
  a.f = f;
  unsigned r = (a.u + 0x7FFFu + ((a.u >> 16) & 1u)) >> 16;  // RN-even
  return (u16)r;
}

// ---------------------------------------------------------------------------
// Prep: fp32 -> bf16 copies of x and y, plus per-row sum of squares.
// ---------------------------------------------------------------------------
__global__ __launch_bounds__(128) void rbf_prep(
    const float* __restrict__ x, const float* __restrict__ y,
    u16* __restrict__ xb, u16* __restrict__ yb,
    float* __restrict__ xsq, float* __restrict__ ysq,
    int N, int M, int D) {
  int row = blockIdx.x;
  const float* src;
  u16* dst;
  float* sq;
  if (row < N) {
    src = x + (size_t)row * D;
    dst = xb + (size_t)row * D;
    sq = xsq + row;
  } else {
    int r = row - N;
    src = y + (size_t)r * D;
    dst = yb + (size_t)r * D;
    sq = ysq + r;
  }
  int t = threadIdx.x;
  float4 v = reinterpret_cast<const float4*>(src)[t];
  float s = v.x * v.x + v.y * v.y + v.z * v.z + v.w * v.w;
  ushort4 o;
  o.x = f2bf(v.x);
  o.y = f2bf(v.y);
  o.z = f2bf(v.z);
  o.w = f2bf(v.w);
  reinterpret_cast<ushort4*>(dst)[t] = o;
  #pragma unroll
  for (int off = 32; off > 0; off >>= 1) s += __shfl_down(s, off, 64);
  __shared__ float red[2];
  if ((t & 63) == 0) red[t >> 6] = s;
  __syncthreads();
  if (t == 0) sq[0] = red[0] + red[1];
}

// ---------------------------------------------------------------------------
// FINAL (R13 = verified best, 112.45 us): 128x128 tile, BK=64, 4 waves
// (2Mx2N), LDS 64 KiB dbuf -> 2 blocks/CU; 3-bit chunk^=(row&7) swizzle
// both sides; counted vmcnt(8) 2-iteration lookahead; 2 barriers/K-tile;
// swapped MFMA operands -> D[j][i] -> float4 stores; column-band supertile;
// exp2-fused epilogue with hoisted norm loads; no setprio (m190: null on
// 2-phase structures).
// Plateau evidence (15 variants, R0-R14): all structural alternatives
// (8-phase, 256^2, BK32, 4 blk/CU, direct-global / hybrid / wave-private
// feeds, nt-stores, consolidation) land 104-124 us GEMM or worse; no pipe
// >30% busy; residue = distributed pipeline fill/drain + wait states that
// 8 K-tiles cannot amortize at HIP-source scheduling depth.
// ---------------------------------------------------------------------------
#define BM 128
#define BN 128
#define BK 64

__global__ __launch_bounds__(256, 2) void rbf_gemm(
    const u16* __restrict__ xb, const u16* __restrict__ yb,
    const float* __restrict__ xsq, const float* __restrict__ ysq,
    const float* __restrict__ gptr, float* __restrict__ out,
    int N, int M, int D) {
  __shared__ u16 lds[2][2][BM * BK];  // 64 KiB

  int bid = blockIdx.x;
  int nbr = N / BM, nbc = M / BN;
  int trow, tcol;
  if (nbr == 64 && nbc == 64) {
    // XCD x owns tile-columns x*8..x*8+7, walked in 8x8-tile regions
    // (column-major inside a region): panels stay L2-resident per XCD.
    int xcd = bid & 7;
    int s = bid >> 3;        // 0..511
    int gr = s >> 6;         // region row 0..7
    int q = s & 63;          // within-region, column-major
    trow = gr * 8 + (q & 7);
    tcol = xcd * 8 + (q >> 3);
  } else {
    int cpx = gridDim.x >> 3;
    int swz = (bid & 7) * cpx + (bid >> 3);
    trow = swz / nbc;
    tcol = swz % nbc;
  }
  int brow = trow * BM;
  int bcol = tcol * BN;

  int tid = threadIdx.x;
  int w = tid >> 6;       // wave 0..3
  int lane = tid & 63;
  int wm = w >> 1;        // 0..1 row half (64 rows)
  int wn = w & 1;         // 0..1 col half (64 cols)
  int fr = lane & 15;
  int fq = lane >> 4;

  // --- staging: wave w stages rows w*32..w*32+31 of A and B tiles ---
  int srow = lane >> 3;                        // 0..7
  int scol = ((lane & 7) ^ srow) * 8;          // inverse-swizzled source col
  const u16* xsrc = xb + (size_t)(brow + w * 32 + srow) * D + scol;
  const u16* ysrc = yb + (size_t)(bcol + w * 32 + srow) * D + scol;
  int sdst = w * 2048;  // 32 rows * 64 elems

  // --- fragment read offsets: chunk ^= (row&7) ---
  int cxor = (fr & 7) * 8;
  int colx0 = (fq * 8) ^ cxor;        // kk=0
  int colx1 = (32 + fq * 8) ^ cxor;   // kk=1
  int arow0 = (wm * 64 + fr) * 64;
  int brow0 = (wn * 64 + fr) * 64;

  // --- hoisted epilogue constants & norm loads (latency-free in prologue) ---
  float gl2 = gptr[0] * 1.44269504088896f;  // gamma * log2(e)
  float m2gl2 = 2.0f * gl2;
  float gxs[4];
  float4 gys[4];
  #pragma unroll
  for (int m = 0; m < 4; ++m)
    gxs[m] = gl2 * xsq[brow + wm * 64 + m * 16 + fr];
  #pragma unroll
  for (int n = 0; n < 4; ++n) {
    float4 t4 = *reinterpret_cast<const float4*>(
        &ysq[bcol + wn * 64 + n * 16 + fq * 4]);
    gys[n].x = gl2 * t4.x;
    gys[n].y = gl2 * t4.y;
    gys[n].z = gl2 * t4.z;
    gys[n].w = gl2 * t4.w;
  }

  f32x4 acc[4][4];
  #pragma unroll
  for (int m = 0; m < 4; ++m)
    #pragma unroll
    for (int n = 0; n < 4; ++n)
      acc[m][n] = (f32x4){0.f, 0.f, 0.f, 0.f};

  auto stage = [&](int kt, int b) {
    const u16* xs = xsrc + kt * 64;
    const u16* ys = ysrc + kt * 64;
    u16* la = &lds[b][0][sdst];
    u16* lb = &lds[b][1][sdst];
    #pragma unroll
    for (int i = 0; i < 4; ++i)
      gload_lds16(xs + (size_t)i * 8 * D, la + i * 512);
    #pragma unroll
    for (int i = 0; i < 4; ++i)
      gload_lds16(ys + (size_t)i * 8 * D, lb + i * 512);
  };

  int nkt = D >> 6;  // 8
  stage(0, 0);
  stage(1, 1);
  for (int t = 0; t < nkt; ++t) {
    int b = t & 1;
    // my 8 loads of tile t landed (8 of tile t+1 stay in flight)
    if (t + 1 < nkt)
      asm volatile("s_waitcnt vmcnt(8)" ::: "memory");
    else
      asm volatile("s_waitcnt vmcnt(0)" ::: "memory");
    __builtin_amdgcn_sched_barrier(0);
    __builtin_amdgcn_s_barrier();  // all waves' tile-t data visible
    __builtin_amdgcn_sched_barrier(0);

    const u16* A = &lds[b][0][0];
    const u16* B = &lds[b][1][0];
    bf16x8 af[4][2], bf[4][2];
    #pragma unroll
    for (int m = 0; m < 4; ++m) {
      af[m][0] = *(const bf16x8*)&A[arow0 + m * 1024 + colx0];
      af[m][1] = *(const bf16x8*)&A[arow0 + m * 1024 + colx1];
    }
    #pragma unroll
    for (int n = 0; n < 4; ++n) {
      bf[n][0] = *(const bf16x8*)&B[brow0 + n * 1024 + colx0];
      bf[n][1] = *(const bf16x8*)&B[brow0 + n * 1024 + colx1];
    }

    // Swapped operands: D[j][i], j = fq*4 + r, i = fr. (no setprio: m190)
    #pragma unroll
    for (int m = 0; m < 4; ++m)
      #pragma unroll
      for (int n = 0; n < 4; ++n) {
        acc[m][n] = __builtin_amdgcn_mfma_f32_16x16x32_bf16(
            bf[n][0], af[m][0], acc[m][n], 0, 0, 0);
        acc[m][n] = __builtin_amdgcn_mfma_f32_16x16x32_bf16(
            bf[n][1], af[m][1], acc[m][n], 0, 0, 0);
      }

    // my ds_reads of buf b done before anyone re-stages into it
    asm volatile("s_waitcnt lgkmcnt(0)" ::: "memory");
    __builtin_amdgcn_sched_barrier(0);
    __builtin_amdgcn_s_barrier();
    __builtin_amdgcn_sched_barrier(0);
    if (t + 2 < nkt) stage(t + 2, b);
  }

  // Epilogue: out = exp2(2*gl2*acc - gl2*|x|^2 - gl2*|y|^2), clamped <= 2^0.
  #pragma unroll
  for (int m = 0; m < 4; ++m) {
    int i = brow + wm * 64 + m * 16 + fr;
    size_t ro = (size_t)i * M;
    #pragma unroll
    for (int n = 0; n < 4; ++n) {
      int jb = bcol + wn * 64 + n * 16 + fq * 4;
      float4 e;
      e.x = exp2f(fminf(fmaf(m2gl2, acc[m][n][0], -(gxs[m] + gys[n].x)), 0.f));
      e.y = exp2f(fminf(fmaf(m2gl2, acc[m][n][1], -(gxs[m] + gys[n].y)), 0.f));
      e.z = exp2f(fminf(fmaf(m2gl2, acc[m][n][2], -(gxs[m] + gys[n].z)), 0.f));
      e.w = exp2f(fminf(fmaf(m2gl2, acc[m][n][3], -(gxs[m] + gys[n].w)), 0.f));
      *reinterpret_cast<float4*>(&out[ro + jb]) = e;
    }
  }
}

// ---------------------------------------------------------------------------
// Fallback: fp32 LDS-tiled, slow but correct for odd shapes.
// ---------------------------------------------------------------------------
__global__ __launch_bounds__(256) void rbf_naive(
    const float* __restrict__ x, const float* __restrict__ y,
    const float* __restrict__ gptr, float* __restrict__ out,
    int N, int M, int D) {
  __shared__ float xs[16][17];
  __shared__ float ys[16][17];
  int nbn = M / 16;
  int brow = (blockIdx.x / nbn) * 16;
  int bcol = (blockIdx.x % nbn) * 16;
  int ti = threadIdx.x >> 4, tj = threadIdx.x & 15;
  float dacc = 0.f, xacc = 0.f, yacc = 0.f;
  for (int k0 = 0; k0 < D; k0 += 16) {
    xs[ti][tj] = x[(size_t)(brow + ti) * D + k0 + tj];
    ys[ti][tj] = y[(size_t)(bcol + ti) * D + k0 + tj];
    __syncthreads();
    #pragma unroll
    for (int kk = 0; kk < 16; ++kk) {
      float xv = xs[ti][kk], yv = ys[tj][kk];
      dacc += xv * yv;
      xacc += xv * xv;
      yacc += yv * yv;
    }
    __syncthreads();
  }
  float gamma = gptr[0];
  float d2 = fmaxf(xacc + yacc - 2.f * dacc, 0.f);
  out[(size_t)(brow + ti) * M + (bcol + tj)] = __expf(-gamma * d2);
}

// ---------------------------------------------------------------------------
extern "C" void kernel_launch(void* const* d_in, const int* in_sizes, int n_in,
                              void* d_out, int out_size, void* d_ws,
                              size_t ws_size, hipStream_t stream) {
  const float* x = (const float*)d_in[0];
  const float* y = (const float*)d_in[1];
  const float* g = (const float*)d_in[2];
  float* out = (float*)d_out;

  const int D = 512;
  const int N = in_sizes[0] / D;
  const int M = in_sizes[1] / D;

  size_t need = (size_t)(N + M) * D * sizeof(u16) + (size_t)(N + M) * sizeof(float);
  bool shapes_ok = (N % BM == 0) && (M % BN == 0) && (D % BK == 0) && (D / BK >= 2);

  if (ws_size >= need && shapes_ok) {
    u16* xb = (u16*)d_ws;
    u16* yb = xb + (size_t)N * D;
    float* xsq = (float*)(yb + (size_t)M * D);
    float* ysq = xsq + N;

    rbf_prep<<<N + M, 128, 0, stream>>>(x, y, xb, yb, xsq, ysq, N, M, D);
    int nwg = (N / BM) * (M / BN);
    rbf_gemm<<<nwg, 256, 0, stream>>>(xb, yb, xsq, ysq, g, out, N, M, D);
  } else {
    rbf_naive<<<(N / 16) * (M / 16), 256, 0, stream>>>(x, y, g, out, N, M, D);
  }
}